// Round 5
// baseline (878.547 us; speedup 1.0000x reference)
//
#include <hip/hip_runtime.h>
#include <cstdint>
#include <cstddef>

typedef __attribute__((ext_vector_type(8))) short bf16x8;
typedef __attribute__((ext_vector_type(4))) float f32x4;
typedef __attribute__((ext_vector_type(4))) int i32x4;

#define NB 512            // persistent grid: 2 WG/CU x 256 CU, exact capacity

// mid-layer tile: 32 rows x 16 cols, halo 34x18, ks-split staging (4 planes)
#define TR 32
#define TC 16
#define HR 34
#define HC 18
#define HPX (HR * HC)     // 612
#define HPP 613           // plane stride in i32x4 (613*4 % 32 = 20 -> spread)

// last-layer tile: 16x16, halo 18x18, 8 planes
#define LW 18
#define LPX (LW * LW)     // 324
#define LPP 325

#define SH_BYTES 41600    // max(4*613*16=39232, 8*325*16=41600)

__device__ inline unsigned short cvt_bf16_rne(float f) {
    unsigned u = __builtin_bit_cast(unsigned, f);
    u = (u + 0x7FFFu + ((u >> 16) & 1u)) >> 16;
    return (unsigned short)u;
}

__global__ void init_kernel(int* bar) {
    if (threadIdx.x < 16) bar[threadIdx.x] = 0;
}

// device-scope counting barrier; one counter per sync point, zeroed by init.
__device__ inline void gbar(int* bar, int idx) {
    __syncthreads();
    if (threadIdx.x == 0) {
        __hip_atomic_fetch_add(bar + idx, 1, __ATOMIC_ACQ_REL, __HIP_MEMORY_SCOPE_AGENT);
        while (__hip_atomic_load(bar + idx, __ATOMIC_ACQUIRE, __HIP_MEMORY_SCOPE_AGENT) < NB)
            __builtin_amdgcn_s_sleep(1);
    }
    __syncthreads();
}

// ---------------------------------------------------------------------------
// Mid conv layer 64->64 + ReLU, bf16 MFMA implicit GEMM.
// One 32x16 tile per WG (512 jobs). Wave = 8 rows x 16 cols (nf=8, mf=4).
// ks-split: stage 4 ci-octet planes (39 KB), compute 9 taps, repeat.
__device__ inline void mid_layer(const char* __restrict__ actb,
                                 const char* __restrict__ apl,
                                 const float* __restrict__ cb,
                                 char* __restrict__ outb,
                                 int wg, int tid, i32x4* lds) {
    int a = wg >> 7;
    int idx = wg & 127;
    int r0 = (idx >> 4) * TR;
    int c0 = (idx & 15) * TC;
    int lane = tid & 63, wv = tid >> 6;
    int n = lane & 15, q = lane >> 4;
    int rbase = wv * 8;

    f32x4 acc[4][8];
    #pragma unroll
    for (int mf = 0; mf < 4; ++mf) {
        f32x4 bb = *(const f32x4*)(cb + a * 64 + mf * 16 + q * 4);
        #pragma unroll
        for (int nf = 0; nf < 8; ++nf) acc[mf][nf] = bb;
    }

    const char* ap = apl + (size_t)a * 73728 + lane * 16;
    const i32x4* bb0 = lds + q * HPP + rbase * HC + n;

    for (int ks = 0; ks < 2; ++ks) {
        __syncthreads();
        for (int s = tid; s < 4 * HPX; s += 256) {
            int o = s & 3, px = s >> 2;
            int prow = px / HC, pcol = px - prow * HC;
            int grow = r0 - 1 + prow, gcol = c0 - 1 + pcol;
            i32x4 v = {0, 0, 0, 0};
            if ((unsigned)grow < 256u && (unsigned)gcol < 256u)
                v = *(const i32x4*)(actb + (((size_t)((a << 16) + (grow << 8) + gcol)) << 7)
                                    + ks * 64 + (o << 4));
            lds[o * HPP + px] = v;
        }
        __syncthreads();

        const char* apk = ap + ks * 36864;
        #pragma unroll
        for (int tap = 0; tap < 9; ++tap) {
            const int ty = tap / 3, tx = tap - ty * 3;
            bf16x8 Af[4], Bf[8];
            #pragma unroll
            for (int mf = 0; mf < 4; ++mf)
                Af[mf] = __builtin_bit_cast(bf16x8,
                    *(const i32x4*)(apk + tap * 4096 + mf * 1024));
            #pragma unroll
            for (int nf = 0; nf < 8; ++nf)
                Bf[nf] = __builtin_bit_cast(bf16x8, bb0[(nf + ty) * HC + tx]);
            #pragma unroll
            for (int mf = 0; mf < 4; ++mf)
                #pragma unroll
                for (int nf = 0; nf < 8; ++nf)
                    acc[mf][nf] = __builtin_amdgcn_mfma_f32_16x16x32_bf16(
                        Af[mf], Bf[nf], acc[mf][nf], 0, 0, 0);
        }
    }

    #pragma unroll
    for (int nf = 0; nf < 8; ++nf) {
        int grow = r0 + rbase + nf;
        int gcol = c0 + n;
        char* ob = outb + (((size_t)((a << 16) + (grow << 8) + gcol)) << 7) + q * 8;
        #pragma unroll
        for (int mf = 0; mf < 4; ++mf) {
            f32x4 v = acc[mf][nf];
            unsigned d0 = (unsigned)cvt_bf16_rne(fmaxf(v.x, 0.0f))
                        | ((unsigned)cvt_bf16_rne(fmaxf(v.y, 0.0f)) << 16);
            unsigned d1 = (unsigned)cvt_bf16_rne(fmaxf(v.z, 0.0f))
                        | ((unsigned)cvt_bf16_rne(fmaxf(v.w, 0.0f)) << 16);
            uint2 st; st.x = d0; st.y = d1;
            *(uint2*)(ob + mf * 32) = st;
        }
    }
}

// ---------------------------------------------------------------------------
__global__ __launch_bounds__(256, 2)
void mega_kernel(const float* __restrict__ xv,
                 const float* __restrict__ yv,
                 const void*  __restrict__ xmask,
                 const int*   __restrict__ actions,
                 const float* __restrict__ weight,
                 const float* __restrict__ cw0, const float* __restrict__ cb0,
                 const float* __restrict__ cw1, const float* __restrict__ cb1,
                 const float* __restrict__ cw2, const float* __restrict__ cb2,
                 const float* __restrict__ cw3, const float* __restrict__ cb3,
                 const float* __restrict__ cw4, const float* __restrict__ cb4,
                 float* __restrict__ out,
                 unsigned short* __restrict__ bufA,
                 unsigned short* __restrict__ bufB,
                 char* __restrict__ apack,
                 float* __restrict__ W_a,
                 int* __restrict__ flag,
                 int* __restrict__ bar) {
    __shared__ char shraw[SH_BYTES] __attribute__((aligned(16)));
    i32x4* lds = (i32x4*)shraw;
    int wg = blockIdx.x, tid = threadIdx.x;

    // ================= P0: conv_first (2 rows/WG) + A-pack + mask detect ====
    for (int j = 0; j < 2; ++j) {
        int job = wg * 2 + j;         // [0,1024)
        int a = job >> 8, y = job & 255, x = tid;
        float p[3][3];
        #pragma unroll
        for (int ty = 0; ty < 3; ++ty)
            #pragma unroll
            for (int tx = 0; tx < 3; ++tx) {
                int py = y + ty - 1, px = x + tx - 1;
                p[ty][tx] = ((unsigned)py < 256u && (unsigned)px < 256u)
                            ? weight[py * 256 + px] : 0.0f;
            }
        const float* w = cw0 + (size_t)a * 64 * 9;
        const float* b = cb0 + a * 64;
        unsigned pk[32];
        #pragma unroll
        for (int co = 0; co < 64; ++co) {
            const float* wc = w + co * 9;
            float acc = b[co];
            #pragma unroll
            for (int ty = 0; ty < 3; ++ty)
                #pragma unroll
                for (int tx = 0; tx < 3; ++tx)
                    acc = fmaf(wc[ty * 3 + tx], p[ty][tx], acc);
            acc = fmaxf(acc, 0.0f);
            unsigned short hv = cvt_bf16_rne(acc);
            if (co & 1) pk[co >> 1] |= ((unsigned)hv << 16);
            else        pk[co >> 1] = (unsigned)hv;
        }
        char* ob = (char*)bufA + (((size_t)((a << 16) + (y << 8) + x)) << 7);
        #pragma unroll
        for (int k = 0; k < 8; ++k)
            *(i32x4*)(ob + k * 16) = *(i32x4*)&pk[k * 4];
    }

    {   // A-frag pack: 55296 items; WGs 0..215 cover them 1:1
        int i = wg * 256 + tid;
        if (i < 55296) {
            int layer = i / 18432;
            int r = i - layer * 18432;
            int lane = r & 63, mf = (r >> 6) & 3;
            int t = r >> 8;
            int tap = t % 9, t2 = t / 9;
            int ks = t2 & 1, a = t2 >> 1;
            int nn = lane & 15, qq = lane >> 4;
            int co = mf * 16 + nn;
            int ci0 = ks * 32 + qq * 8;
            const float* cw = (layer == 0) ? cw1 : (layer == 1) ? cw2 : cw3;
            unsigned d[4];
            #pragma unroll
            for (int jj = 0; jj < 4; ++jj) {
                unsigned short h0 = cvt_bf16_rne(cw[((size_t)(a * 64 + co) * 64 + ci0 + 2 * jj + 0) * 9 + tap]);
                unsigned short h1 = cvt_bf16_rne(cw[((size_t)(a * 64 + co) * 64 + ci0 + 2 * jj + 1) * 9 + tap]);
                d[jj] = (unsigned)h0 | ((unsigned)h1 << 16);
            }
            *(i32x4*)(apack + (size_t)i * 16) = *(i32x4*)d;
        }
    }

    if (wg == 511) {   // mask format detect: 0=int32, 1=bytes, 2=float
        int* red = (int*)shraw;
        if (tid == 0) *red = 0;
        __syncthreads();
        const unsigned* m = (const unsigned*)xmask;
        int f = 0;
        for (int k = 0; k < 128; ++k) {
            unsigned v = m[k * 256 + tid];
            if (v == 0x3F800000u) f |= 2;
            else if (v > 1u) f |= 1;
        }
        if (f) atomicOr(red, f);
        __syncthreads();
        if (tid == 0) *flag = *red;
    }
    gbar(bar, 0);

    // ================= P1..P3: mid layers =================================
    mid_layer((const char*)bufA, apack,          cb1, (char*)bufB, wg, tid, lds);
    gbar(bar, 1);
    mid_layer((const char*)bufB, apack + 294912, cb2, (char*)bufA, wg, tid, lds);
    gbar(bar, 2);
    mid_layer((const char*)bufA, apack + 589824, cb3, (char*)bufB, wg, tid, lds);
    gbar(bar, 3);

    // ================= P4: conv_last (2 tiles/WG) ==========================
    for (int j = 0; j < 2; ++j) {
        int job = wg * 2 + j;          // [0,1024)
        int a = job >> 8;
        int idx = job & 255;
        int r0 = (idx >> 4) * 16, c0 = (idx & 15) * 16;
        __syncthreads();
        for (int s = tid; s < 8 * LPX; s += 256) {
            int o = s & 7, px = s >> 3;
            int prow = px / LW, pcol = px - prow * LW;
            int grow = r0 - 1 + prow, gcol = c0 - 1 + pcol;
            i32x4 v = {0, 0, 0, 0};
            if ((unsigned)grow < 256u && (unsigned)gcol < 256u)
                v = *(const i32x4*)((const char*)bufB +
                    (((size_t)((a << 16) + (grow << 8) + gcol)) << 7) + (o << 4));
            lds[o * LPP + px] = v;
        }
        __syncthreads();

        int lane = tid & 63, wv = tid >> 6;
        int o = lane & 7, pl = lane >> 3;
        float wr[8][9];
        #pragma unroll
        for (int jj = 0; jj < 8; ++jj) {
            const float* wp = cw4 + ((size_t)a * 64 + o * 8 + jj) * 9;
            #pragma unroll
            for (int t = 0; t < 9; ++t) wr[jj][t] = wp[t];
        }
        float bias = cb4[a];
        const i32x4* lbase = lds + o * LPP;
        #pragma unroll
        for (int i = 0; i < 8; ++i) {
            int r = 2 * i + (wv >> 1);
            int c = ((wv & 1) << 3) + pl;
            float p = 0.0f;
            #pragma unroll
            for (int ty = 0; ty < 3; ++ty)
                #pragma unroll
                for (int tx = 0; tx < 3; ++tx) {
                    i32x4 v = lbase[(r + ty) * LW + (c + tx)];
                    const unsigned* dv = (const unsigned*)&v;
                    #pragma unroll
                    for (int k = 0; k < 4; ++k) {
                        unsigned d = dv[k];
                        float flo = __builtin_bit_cast(float, d << 16);
                        float fhi = __builtin_bit_cast(float, d & 0xFFFF0000u);
                        p = fmaf(flo, wr[2 * k + 0][ty * 3 + tx], p);
                        p = fmaf(fhi, wr[2 * k + 1][ty * 3 + tx], p);
                    }
                }
            p += __shfl_xor(p, 1, 64);
            p += __shfl_xor(p, 2, 64);
            p += __shfl_xor(p, 4, 64);
            if (o == 0)
                W_a[(size_t)((a << 16) + ((r0 + r) << 8) + (c0 + c))] = p + bias;
        }
    }
    gbar(bar, 4);

    // ================= P5: Wy (per-WG, LDS) + logits =======================
    {
        int b = wg >> 4, seg = wg & 15;
        int aact = actions[b];
        const float* yb = yv + b * 256;
        const float* Wp = W_a + (size_t)aact * 65536;
        float accw = 0.0f;
        #pragma unroll 8
        for (int h = 0; h < 256; ++h)
            accw = fmaf(yb[h], Wp[h * 256 + tid], accw);
        float* wyf = (float*)shraw;
        wyf[tid] = accw;
        __syncthreads();

        int lane = tid & 63, wv = tid >> 6;
        int fl = *flag;
        float4 wy4 = *(const float4*)(wyf + lane * 4);
        const float* xb = xv + (size_t)b * 4096 * 256;
        int lb = seg * 256 + wv * 64;
        for (int it = 0; it < 64; ++it) {
            int l = lb + it;
            const float4 x4 = *(const float4*)(xb + (size_t)l * 256 + lane * 4);
            float p = x4.x * wy4.x + x4.y * wy4.y + x4.z * wy4.z + x4.w * wy4.w;
            #pragma unroll
            for (int off = 32; off > 0; off >>= 1)
                p += __shfl_xor(p, off, 64);
            if (lane == 0) {
                size_t mi = (size_t)b * 4096 + l;
                bool msk;
                if (fl & 2)      msk = ((const float*)xmask)[mi] != 0.0f;
                else if (fl & 1) msk = ((const unsigned char*)xmask)[mi] != 0;
                else             msk = ((const int*)xmask)[mi] != 0;
                out[mi] = msk ? -__builtin_inff() : p;
            }
        }
    }
    gbar(bar, 5);

    // ================= P6: softmax (WGs 0..31) =============================
    if (wg < 32) {
        float* row = out + (size_t)wg * 4096;
        float* sred = (float*)shraw;
        int lane = tid & 63, wid = tid >> 6;
        float v[16];
        float m = -__builtin_inff();
        #pragma unroll
        for (int i = 0; i < 16; ++i) { v[i] = row[tid + i * 256]; m = fmaxf(m, v[i]); }
        #pragma unroll
        for (int off = 32; off > 0; off >>= 1) m = fmaxf(m, __shfl_xor(m, off, 64));
        if (lane == 0) sred[wid] = m;
        __syncthreads();
        float M = fmaxf(fmaxf(sred[0], sred[1]), fmaxf(sred[2], sred[3]));
        float s = 0.0f;
        #pragma unroll
        for (int i = 0; i < 16; ++i) { v[i] = expf(v[i] - M); s += v[i]; }
        #pragma unroll
        for (int off = 32; off > 0; off >>= 1) s += __shfl_xor(s, off, 64);
        if (lane == 0) sred[8 + wid] = s;
        __syncthreads();
        float S = sred[8] + sred[9] + sred[10] + sred[11];
        float inv = 1.0f / S;
        #pragma unroll
        for (int i = 0; i < 16; ++i) row[tid + i * 256] = v[i] * inv;
    }
}

// ---------------------------------------------------------------------------
extern "C" void kernel_launch(void* const* d_in, const int* in_sizes, int n_in,
                              void* d_out, int out_size, void* d_ws, size_t ws_size,
                              hipStream_t stream) {
    const float* xv      = (const float*)d_in[0];
    const float* yv      = (const float*)d_in[1];
    const void*  xmask   = d_in[2];
    const int*   actions = (const int*)d_in[3];
    const float* weight  = (const float*)d_in[4];
    const float* cw0 = (const float*)d_in[5];
    const float* cb0 = (const float*)d_in[6];
    const float* cw1 = (const float*)d_in[7];
    const float* cb1 = (const float*)d_in[8];
    const float* cw2 = (const float*)d_in[9];
    const float* cb2 = (const float*)d_in[10];
    const float* cw3 = (const float*)d_in[11];
    const float* cb3 = (const float*)d_in[12];
    const float* cw4 = (const float*)d_in[13];
    const float* cb4 = (const float*)d_in[14];
    float* out = (float*)d_out;

    char* ws = (char*)d_ws;
    unsigned short* bufA = (unsigned short*)ws;                    // 33,554,432 B
    unsigned short* bufB = (unsigned short*)(ws + 33554432);       // 33,554,432 B
    char*  apack = ws + 67108864;                                  // 884,736 B
    float* W_a   = (float*)(ws + 67993600);                        // 1,048,576 B
    int*   flag  = (int*)(ws + 69042176);
    int*   bar   = (int*)(ws + 69042240);                          // 16 ints

    init_kernel<<<1, 64, 0, stream>>>(bar);
    mega_kernel<<<NB, 256, 0, stream>>>(xv, yv, xmask, actions, weight,
                                        cw0, cb0, cw1, cb1, cw2, cb2,
                                        cw3, cb3, cw4, cb4,
                                        out, bufA, bufB, apack, W_a, flag, bar);
}

// Round 6
// 488.331 us; speedup vs baseline: 1.7991x; 1.7991x over previous
//
#include <hip/hip_runtime.h>
#include <cstdint>
#include <cstddef>

typedef __attribute__((ext_vector_type(8))) short bf16x8;
typedef __attribute__((ext_vector_type(4))) float f32x4;
typedef __attribute__((ext_vector_type(4))) int i32x4;

// conv_mid tile: 16x16 px, halo 18x18, ks-split staging (4 ci-octet planes)
#define MW   18
#define MPX  (MW * MW)    // 324 pixels
#define MPP  330          // plane stride in i32x4; 330*4 dwords % 32 = 8 -> planes at banks {0,8,16,24}

// conv_last tile: 16x16, halo 18x18, 8 planes
#define LW  18
#define LPX (LW * LW)
#define LPP 325

__device__ inline unsigned short cvt_bf16_rne(float f) {
    unsigned u = __builtin_bit_cast(unsigned, f);
    u = (u + 0x7FFFu + ((u >> 16) & 1u)) >> 16;
    return (unsigned short)u;
}

// ---------------------------------------------------------------------------
// prep_kernel: conv_first (blocks 0..1023) + weight A-pack for layers 1..3
// (blocks 1024..1239) + mask-format detect (block 1240). 256 threads.
__global__ void prep_kernel(const float* __restrict__ img,
                            const float* __restrict__ cw0,
                            const float* __restrict__ cb0,
                            unsigned short* __restrict__ act,
                            const float* __restrict__ cw1,
                            const float* __restrict__ cw2,
                            const float* __restrict__ cw3,
                            char* __restrict__ apack,
                            const unsigned int* __restrict__ mask,
                            int* __restrict__ flag) {
    int bid = blockIdx.x, tid = threadIdx.x;

    if (bid < 1024) {
        int y = bid & 255, a = bid >> 8, x = tid;
        float p[3][3];
        #pragma unroll
        for (int ty = 0; ty < 3; ++ty)
            #pragma unroll
            for (int tx = 0; tx < 3; ++tx) {
                int py = y + ty - 1, px = x + tx - 1;
                p[ty][tx] = ((unsigned)py < 256u && (unsigned)px < 256u)
                            ? img[py * 256 + px] : 0.0f;
            }
        const float* w = cw0 + (size_t)a * 64 * 9;
        const float* b = cb0 + a * 64;
        unsigned pk[32];
        #pragma unroll
        for (int co = 0; co < 64; ++co) {
            const float* wc = w + co * 9;
            float acc = b[co];
            #pragma unroll
            for (int ty = 0; ty < 3; ++ty)
                #pragma unroll
                for (int tx = 0; tx < 3; ++tx)
                    acc = fmaf(wc[ty * 3 + tx], p[ty][tx], acc);
            acc = fmaxf(acc, 0.0f);
            unsigned short hv = cvt_bf16_rne(acc);
            if (co & 1) pk[co >> 1] |= ((unsigned)hv << 16);
            else        pk[co >> 1] = (unsigned)hv;
        }
        char* ob = (char*)act + (((size_t)((a << 16) + (y << 8) + x)) << 7);
        #pragma unroll
        for (int k = 0; k < 8; ++k)
            *(i32x4*)(ob + k * 16) = *(i32x4*)&pk[k * 4];
        return;
    }

    if (bid < 1240) {
        // A-frag pack: idx within layer = (((a*2+ks)*9+tap)*4+mf)*64+lane
        int idx = (bid - 1024) * 256 + tid;     // 0 .. 55295
        int layer = idx / 18432;
        int r = idx - layer * 18432;
        int lane = r & 63, mf = (r >> 6) & 3;
        int t = r >> 8;
        int tap = t % 9, t2 = t / 9;
        int ks = t2 & 1, a = t2 >> 1;
        int n = lane & 15, q = lane >> 4;
        int co = mf * 16 + n;
        int ci0 = ks * 32 + q * 8;
        const float* cw = (layer == 0) ? cw1 : (layer == 1) ? cw2 : cw3;
        unsigned d[4];
        #pragma unroll
        for (int jj = 0; jj < 4; ++jj) {
            unsigned short h0 = cvt_bf16_rne(cw[((size_t)(a * 64 + co) * 64 + ci0 + 2 * jj + 0) * 9 + tap]);
            unsigned short h1 = cvt_bf16_rne(cw[((size_t)(a * 64 + co) * 64 + ci0 + 2 * jj + 1) * 9 + tap]);
            d[jj] = (unsigned)h0 | ((unsigned)h1 << 16);
        }
        *(i32x4*)(apack + (size_t)idx * 16) = *(i32x4*)d;
        return;
    }

    // mask format detect: 0=int32, 1=bytes, 2=float
    __shared__ int red;
    if (tid == 0) red = 0;
    __syncthreads();
    int f = 0;
    for (int k = 0; k < 128; ++k) {
        unsigned v = mask[k * 256 + tid];
        if (v == 0x3F800000u) f |= 2;
        else if (v > 1u) f |= 1;
    }
    if (f) atomicOr(&red, f);
    __syncthreads();
    if (tid == 0) *flag = red;
}

// ---------------------------------------------------------------------------
// Mid layers 64->64 + ReLU, bf16 MFMA implicit GEMM.
// WG = 256 thr (4 waves), tile 16x16 px; wave = 4 rows x 16 cols (nf=4,mf=4).
// LDS: ks-reused halo buffer, 4 ci-octet planes x 330 i32x4 = 21 KB ->
// 4 WG/CU (16 waves/CU). grid dim3(16,16,4) = 1024 WGs, 1 job each.
__global__ __launch_bounds__(256, 4)
void conv_mid_mfma(const unsigned short* __restrict__ act_in,
                   const char* __restrict__ apack_l,
                   const float* __restrict__ cb,
                   unsigned short* __restrict__ act_out) {
    __shared__ i32x4 lds4[4 * MPP];   // 21120 B
    int tid = threadIdx.x;
    int a = blockIdx.z;
    int r0 = blockIdx.y * 16, c0 = blockIdx.x * 16;
    const char* actb = (const char*)act_in;

    int lane = tid & 63, wv = tid >> 6;
    int n = lane & 15, q = lane >> 4;
    int rbase = wv * 4;

    f32x4 acc[4][4];
    #pragma unroll
    for (int mf = 0; mf < 4; ++mf) {
        f32x4 bb = *(const f32x4*)(cb + a * 64 + mf * 16 + q * 4);
        #pragma unroll
        for (int nf = 0; nf < 4; ++nf) acc[mf][nf] = bb;
    }

    const char* ap = apack_l + (size_t)a * 73728 + lane * 16;
    const i32x4* bb0 = lds4 + q * MPP + rbase * MW + n;

    for (int ks = 0; ks < 2; ++ks) {
        __syncthreads();   // protect previous ks reads before overwrite
        for (int s = tid; s < 4 * MPX; s += 256) {
            int o = s & 3, px = s >> 2;
            int prow = px / MW, pcol = px - prow * MW;
            int grow = r0 - 1 + prow, gcol = c0 - 1 + pcol;
            i32x4 v = {0, 0, 0, 0};
            if ((unsigned)grow < 256u && (unsigned)gcol < 256u)
                v = *(const i32x4*)(actb + (((size_t)((a << 16) + (grow << 8) + gcol)) << 7)
                                    + ks * 64 + (o << 4));
            lds4[o * MPP + px] = v;
        }
        __syncthreads();

        const char* apk = ap + ks * 36864;
        #pragma unroll
        for (int tap = 0; tap < 9; ++tap) {
            const int ty = tap / 3, tx = tap - ty * 3;
            bf16x8 Af[4], Bf[4];
            #pragma unroll
            for (int mf = 0; mf < 4; ++mf)
                Af[mf] = __builtin_bit_cast(bf16x8,
                    *(const i32x4*)(apk + tap * 4096 + mf * 1024));
            #pragma unroll
            for (int nf = 0; nf < 4; ++nf)
                Bf[nf] = __builtin_bit_cast(bf16x8, bb0[(nf + ty) * MW + tx]);
            #pragma unroll
            for (int mf = 0; mf < 4; ++mf)
                #pragma unroll
                for (int nf = 0; nf < 4; ++nf)
                    acc[mf][nf] = __builtin_amdgcn_mfma_f32_16x16x32_bf16(
                        Af[mf], Bf[nf], acc[mf][nf], 0, 0, 0);
        }
    }

    #pragma unroll
    for (int nf = 0; nf < 4; ++nf) {
        int grow = r0 + rbase + nf;
        int gcol = c0 + n;
        char* ob = (char*)act_out + (((size_t)((a << 16) + (grow << 8) + gcol)) << 7) + q * 8;
        #pragma unroll
        for (int mf = 0; mf < 4; ++mf) {
            f32x4 v = acc[mf][nf];
            unsigned d0 = (unsigned)cvt_bf16_rne(fmaxf(v.x, 0.0f))
                        | ((unsigned)cvt_bf16_rne(fmaxf(v.y, 0.0f)) << 16);
            unsigned d1 = (unsigned)cvt_bf16_rne(fmaxf(v.z, 0.0f))
                        | ((unsigned)cvt_bf16_rne(fmaxf(v.w, 0.0f)) << 16);
            uint2 st; st.x = d0; st.y = d1;
            *(uint2*)(ob + mf * 32) = st;
        }
    }
}

// ---------------------------------------------------------------------------
// Layer 4: 64 -> 1, no ReLU, fp32 out. LDS-tiled 16x16 (18x18 halo).
// 8 lanes/pixel, width-8 shuffle reduce. grid dim3(16,16,4), 256 threads.
__global__ __launch_bounds__(256, 3)
void conv_last_kernel(const unsigned short* __restrict__ act,
                      const float* __restrict__ cw4,
                      const float* __restrict__ cb4,
                      float* __restrict__ W_a) {
    __shared__ i32x4 lds4[8 * LPP];
    int tid = threadIdx.x;
    int a = blockIdx.z;
    int r0 = blockIdx.y * 16, c0 = blockIdx.x * 16;
    const char* actb = (const char*)act;

    for (int s = tid; s < 8 * LPX; s += 256) {
        int o = s & 7, px = s >> 3;
        int prow = px / LW, pcol = px - prow * LW;
        int grow = r0 - 1 + prow, gcol = c0 - 1 + pcol;
        i32x4 v = {0, 0, 0, 0};
        if ((unsigned)grow < 256u && (unsigned)gcol < 256u)
            v = *(const i32x4*)(actb + (((size_t)((a << 16) + (grow << 8) + gcol)) << 7) + (o << 4));
        lds4[o * LPP + px] = v;
    }
    __syncthreads();

    int lane = tid & 63, wv = tid >> 6;
    int o = lane & 7, pl = lane >> 3;

    float wr[8][9];
    #pragma unroll
    for (int j = 0; j < 8; ++j) {
        const float* wp = cw4 + ((size_t)a * 64 + o * 8 + j) * 9;
        #pragma unroll
        for (int t = 0; t < 9; ++t) wr[j][t] = wp[t];
    }
    float bias = cb4[a];
    const i32x4* lbase = lds4 + o * LPP;

    #pragma unroll
    for (int i = 0; i < 8; ++i) {
        int r = 2 * i + (wv >> 1);
        int c = ((wv & 1) << 3) + pl;
        float p = 0.0f;
        #pragma unroll
        for (int ty = 0; ty < 3; ++ty)
            #pragma unroll
            for (int tx = 0; tx < 3; ++tx) {
                i32x4 v = lbase[(r + ty) * LW + (c + tx)];
                const unsigned* dv = (const unsigned*)&v;
                #pragma unroll
                for (int k = 0; k < 4; ++k) {
                    unsigned d = dv[k];
                    float flo = __builtin_bit_cast(float, d << 16);
                    float fhi = __builtin_bit_cast(float, d & 0xFFFF0000u);
                    p = fmaf(flo, wr[2 * k + 0][ty * 3 + tx], p);
                    p = fmaf(fhi, wr[2 * k + 1][ty * 3 + tx], p);
                }
            }
        p += __shfl_xor(p, 1, 64);
        p += __shfl_xor(p, 2, 64);
        p += __shfl_xor(p, 4, 64);
        if (o == 0)
            W_a[(size_t)((a << 16) + ((r0 + r) << 8) + (c0 + c))] = p + bias;
    }
}

// ---------------------------------------------------------------------------
// Fused Wy + logits: per WG recompute Wy[b] into LDS (1 MB W_a is L2/L3-hot),
// then 256 seq positions. grid dim3(16 segs, 32 b), 256 threads.
__global__ void wy_logits_kernel(const float* __restrict__ xv,
                                 const float* __restrict__ yv,
                                 const void* __restrict__ xmask,
                                 const int* __restrict__ actions,
                                 const float* __restrict__ W_a,
                                 const int* __restrict__ flag,
                                 float* __restrict__ out) {
    __shared__ float wyf[256];
    int tid = threadIdx.x;
    int b = blockIdx.y, seg = blockIdx.x;
    int aact = actions[b];
    const float* Wp = W_a + (size_t)aact * 65536;
    const float* yb = yv + b * 256;
    float accw = 0.0f;
    #pragma unroll 8
    for (int h = 0; h < 256; ++h)
        accw = fmaf(yb[h], Wp[h * 256 + tid], accw);
    wyf[tid] = accw;
    __syncthreads();

    int lane = tid & 63, wv = tid >> 6;
    int fl = *flag;
    float4 wy4 = *(const float4*)(wyf + lane * 4);
    const float* xb = xv + (size_t)b * 4096 * 256;
    int lb = seg * 256 + wv * 64;
    for (int it = 0; it < 64; ++it) {
        int l = lb + it;
        const float4 x4 = *(const float4*)(xb + (size_t)l * 256 + lane * 4);
        float p = x4.x * wy4.x + x4.y * wy4.y + x4.z * wy4.z + x4.w * wy4.w;
        #pragma unroll
        for (int off = 32; off > 0; off >>= 1)
            p += __shfl_xor(p, off, 64);
        if (lane == 0) {
            size_t mi = (size_t)b * 4096 + l;
            bool msk;
            if (fl & 2)      msk = ((const float*)xmask)[mi] != 0.0f;
            else if (fl & 1) msk = ((const unsigned char*)xmask)[mi] != 0;
            else             msk = ((const int*)xmask)[mi] != 0;
            out[mi] = msk ? -__builtin_inff() : p;
        }
    }
}

// ---------------------------------------------------------------------------
__global__ void softmax_kernel(float* __restrict__ out) {
    int b = blockIdx.x, tid = threadIdx.x;
    int lane = tid & 63, wid = tid >> 6;
    float* row = out + (size_t)b * 4096;
    float v[4];
    float m = -__builtin_inff();
    #pragma unroll
    for (int i = 0; i < 4; ++i) { v[i] = row[tid + i * 1024]; m = fmaxf(m, v[i]); }
    #pragma unroll
    for (int off = 32; off > 0; off >>= 1) m = fmaxf(m, __shfl_xor(m, off, 64));
    __shared__ float redm[16];
    __shared__ float reds[16];
    if (lane == 0) redm[wid] = m;
    __syncthreads();
    float M = redm[0];
    #pragma unroll
    for (int j = 1; j < 16; ++j) M = fmaxf(M, redm[j]);
    float s = 0.0f;
    #pragma unroll
    for (int i = 0; i < 4; ++i) { v[i] = expf(v[i] - M); s += v[i]; }
    #pragma unroll
    for (int off = 32; off > 0; off >>= 1) s += __shfl_xor(s, off, 64);
    if (lane == 0) reds[wid] = s;
    __syncthreads();
    float S = 0.0f;
    #pragma unroll
    for (int j = 0; j < 16; ++j) S += reds[j];
    float inv = 1.0f / S;
    #pragma unroll
    for (int i = 0; i < 4; ++i) row[tid + i * 1024] = v[i] * inv;
}

// ---------------------------------------------------------------------------
extern "C" void kernel_launch(void* const* d_in, const int* in_sizes, int n_in,
                              void* d_out, int out_size, void* d_ws, size_t ws_size,
                              hipStream_t stream) {
    const float* xv      = (const float*)d_in[0];
    const float* yv      = (const float*)d_in[1];
    const void*  xmask   = d_in[2];
    const int*   actions = (const int*)d_in[3];
    const float* weight  = (const float*)d_in[4];
    const float* cw0 = (const float*)d_in[5];
    const float* cb0 = (const float*)d_in[6];
    const float* cw1 = (const float*)d_in[7];
    const float* cb1 = (const float*)d_in[8];
    const float* cw2 = (const float*)d_in[9];
    const float* cb2 = (const float*)d_in[10];
    const float* cw3 = (const float*)d_in[11];
    const float* cb3 = (const float*)d_in[12];
    const float* cw4 = (const float*)d_in[13];
    const float* cb4 = (const float*)d_in[14];
    float* out = (float*)d_out;

    char* ws = (char*)d_ws;
    unsigned short* bufA = (unsigned short*)ws;                    // 33,554,432 B
    unsigned short* bufB = (unsigned short*)(ws + 33554432);       // 33,554,432 B
    char*  apack = ws + 67108864;                                  // 884,736 B
    float* W_a   = (float*)(ws + 67993600);                        // 1,048,576 B
    int*   flag  = (int*)(ws + 69042176);

    prep_kernel<<<1241, 256, 0, stream>>>(weight, cw0, cb0, bufA,
                                          cw1, cw2, cw3, apack,
                                          (const unsigned int*)xmask, flag);

    conv_mid_mfma<<<dim3(16, 16, 4), 256, 0, stream>>>(bufA, apack,          cb1, bufB);
    conv_mid_mfma<<<dim3(16, 16, 4), 256, 0, stream>>>(bufB, apack + 294912, cb2, bufA);
    conv_mid_mfma<<<dim3(16, 16, 4), 256, 0, stream>>>(bufA, apack + 589824, cb3, bufB);
    conv_last_kernel<<<dim3(16, 16, 4), 256, 0, stream>>>(bufB, cw4, cb4, W_a);

    wy_logits_kernel<<<dim3(16, 32), 256, 0, stream>>>(xv, yv, xmask, actions,
                                                       W_a, flag, out);
    softmax_kernel<<<32, 1024, 0, stream>>>(out);
}